// Round 5
// baseline (169.249 us; speedup 1.0000x reference)
//
#include <hip/hip_runtime.h>
#include <hip/hip_bf16.h>
#include <math.h>

#define Bn   4
#define CIN  128
#define Hh   64
#define Ww   64
#define HW   4096
#define CMID 64
#define KOC  100      // (scale*k_up)^2
#define H2   128
#define W2d  128
#define HW2  16384
#define KUP  5
#define BN_EPS 1e-5f

typedef __attribute__((ext_vector_type(4)))  short  short4v;
typedef __attribute__((ext_vector_type(8)))  short  short8v;
typedef __attribute__((ext_vector_type(16))) float  float16v;

__device__ __forceinline__ ushort f2bf(float v) {
    __hip_bfloat16 h = __float2bfloat16(v);
    return *(ushort*)&h;
}

// ---------------- Kernel A: 1x1 conv + BN + SiLU -> W1b NHWC bf16 [b][pix][64]
// block = (b, 16-pixel tile); wave = one 4-pixel group x all 64 co.
// cw staged in LDS [64][129] (pad -> conflict-free); X loads are wave-broadcast.
// Piggyback: first 288 blocks also build Abf[tap][kop 128][cm 64] bf16 (ko pad 0).
__global__ __launch_bounds__(256) void comp_kernel(
    const float* __restrict__ X,
    const float* __restrict__ cw,
    const float* __restrict__ cg,
    const float* __restrict__ cb,
    const float* __restrict__ ew,
    ushort* __restrict__ W1b,       // [b][pix][64] bf16
    ushort* __restrict__ Abf)       // [9][128][64]
{
    __shared__ float cwS[64 * 129];

    int tid = threadIdx.x;
    int blk = blockIdx.x;

    // stage weights: 64 rows x 128 ci
    for (int i = tid; i < 64 * 128; i += 256) {
        int co_s = i >> 7, ci_s = i & 127;
        cwS[co_s * 129 + ci_s] = cw[i];
    }

    if (blk < 288) {                // A-prep: 288*256 = 73728 = 9*128*64
        int i   = blk * 256 + tid;
        int cm  = i & 63;
        int kop = (i >> 6) & 127;
        int tap = i >> 13;
        float v = (kop < KOC) ? ew[((size_t)(kop * CMID + cm)) * 9 + tap] : 0.f;
        Abf[i] = f2bf(v);
    }
    __syncthreads();

    int b   = blk >> 8;                       // 1024 blocks: b(4) x 256 tiles
    int pix = ((blk & 255) << 4) + ((tid >> 6) << 2);   // 16-pix tile, 4 per wave
    int co  = tid & 63;

    const float* xb = X + (size_t)b * CIN * HW + pix;
    const float* wrow = cwS + co * 129;
    float a0 = 0.f, a1 = 0.f, a2 = 0.f, a3 = 0.f;

#pragma unroll 4
    for (int ci = 0; ci < CIN; ++ci) {
        float4 xv = *(const float4*)(xb + (size_t)ci * HW);   // wave-broadcast
        float w = wrow[ci];
        a0 += xv.x * w; a1 += xv.y * w; a2 += xv.z * w; a3 += xv.w * w;
    }

    float inv_s = rsqrtf(1.0f + BN_EPS);
    float s0 = cg[co] * inv_s, bb0 = cb[co];
    float r[4] = {a0, a1, a2, a3};
    ushort* wp = W1b + ((size_t)b * HW + pix) * 64 + co;
#pragma unroll
    for (int i = 0; i < 4; ++i) {
        float v = r[i] * s0 + bb0;
        v = v / (1.f + expf(-v));
        wp[(size_t)i * 64] = f2bf(v);       // 64 lanes -> 128B contiguous
    }
}

// ---------------- Kernel B: 3x3 conv (MFMA) + BN + per-sub softmax + CARAFE
// block = (b, h, w-half, CHANNEL-QUARTER): 32 coarse pixels x 32 channels.
// Grid 2048 (4x round-3): MFMA+softmax phases are redundantly recomputed per
// channel-quarter (MfmaUtil was 1.4% -- free), carafe sweep is 4 stages not 16.
// 6 blocks/CU resident (22.9 KB LDS) vs round-3's 2 -> latency actually hidden.
// LDS arena (time-multiplexed, barriers separate lifetimes):
//   [0,14688)        Bs    : 3*34*72 ushort      (phase 1)
//   [14688,18784)    redm  : [4][8][32] float    (phase 2)
//   [18784,22880)    reds  : [4][8][32] float    (phase 2)
//   [0,12800)        wsL   : [100][32] float     (phase 3; Bs dead)
//   [12800,18560)    xs    : [8][5][36] float    (phase 3; redm dead)
__global__ __launch_bounds__(256) void enc_carafe_kernel(
    const ushort* __restrict__ W1b_us,   // [b][pix][64] bf16
    const ushort* __restrict__ Abf,      // [9][128][64] bf16
    const float* __restrict__ eg,
    const float* __restrict__ eb,
    const float* __restrict__ X,
    float* __restrict__ out)
{
    __shared__ __align__(16) char smem[22880];
    ushort* Bs   = (ushort*)smem;
    float*  redm = (float*)(smem + 14688);
    float*  reds = (float*)(smem + 18784);
    float*  wsL  = (float*)smem;
    float*  xs   = (float*)(smem + 12800);

    int bid   = blockIdx.x;              // (((b*64+h)*2+whalf)<<2)|cg4 -> 2048
    int cg4   = bid & 3;                 // channel quarter: c in [cg4*32, +32)
    int rest  = bid >> 2;
    int whalf = rest & 1;
    int h     = (rest >> 1) & 63;
    int b     = rest >> 7;
    int w0    = whalf * 32;
    int tid   = threadIdx.x;

    // ---- phase 1: stage B tile (bf16-pair granularity, coalesced in cm) ----
    const unsigned* src  = (const unsigned*)W1b_us;  // [b][pix][32] u32 pairs
    unsigned*       dstu = (unsigned*)Bs;            // w-slot stride 36 uints
    for (int i = tid; i < 3 * 34 * 32; i += 256) {
        int cp = i & 31;
        int t  = i >> 5;
        int wl = t % 34;
        int r  = t / 34;
        int gr = h - 1 + r, gw = w0 - 1 + wl;
        unsigned val = 0u;
        if ((unsigned)gr < 64u && (unsigned)gw < 64u)
            val = src[((size_t)b * HW + gr * 64 + gw) * 32 + cp];
        dstu[(r * 34 + wl) * 36 + cp] = val;
    }
    __syncthreads();

    int lane = tid & 63;
    int wid  = tid >> 6;                 // M-tile: ko base = wid*32
    int n    = lane & 31;
    int q    = lane >> 5;                // 0/1 -> k half

    float16v acc;
#pragma unroll
    for (int i = 0; i < 16; ++i) acc[i] = 0.f;

    const ushort* Arow = Abf + ((size_t)(wid * 32 + n)) * 64 + q * 8;

#pragma unroll
    for (int tap = 0; tap < 9; ++tap) {
        int dy = tap / 3, dx = tap % 3;
        int bbase = ((dy * 34) + n + dx) * 72 + q * 8;     // ushort idx, 16B aligned
        const ushort* Atap = Arow + (size_t)tap * 128 * 64;
#pragma unroll
        for (int c = 0; c < 4; ++c) {
            short8v a = *(const short8v*)(Atap + c * 16);
            short8v bf = *(const short8v*)(Bs + bbase + c * 16);
            acc = __builtin_amdgcn_mfma_f32_32x32x16_bf16(a, bf, acc, 0, 0, 0);
        }
    }

    // ---- phase 2: BN + per-subpixel softmax ----
    // reg = 4g+j -> row = j + 8g + 4q -> ko = wid*32 + 8g + 4q + j; ko mod 4 = j.
    float inv_s = rsqrtf(1.0f + BN_EPS);
    int   widq  = wid * 2 + q;

    float v[16];
    float pmax[4] = {-1e30f, -1e30f, -1e30f, -1e30f};
#pragma unroll
    for (int g = 0; g < 4; ++g) {
        int base = wid * 32 + 8 * g + 4 * q;
        if (base < KOC) {
            float4 gg = *(const float4*)(eg + base);
            float4 bb = *(const float4*)(eb + base);
            float v0 = acc[4*g+0] * (gg.x * inv_s) + bb.x;
            float v1 = acc[4*g+1] * (gg.y * inv_s) + bb.y;
            float v2 = acc[4*g+2] * (gg.z * inv_s) + bb.z;
            float v3 = acc[4*g+3] * (gg.w * inv_s) + bb.w;
            v[4*g+0] = v0; v[4*g+1] = v1; v[4*g+2] = v2; v[4*g+3] = v3;
            pmax[0] = fmaxf(pmax[0], v0);
            pmax[1] = fmaxf(pmax[1], v1);
            pmax[2] = fmaxf(pmax[2], v2);
            pmax[3] = fmaxf(pmax[3], v3);
        } else {
            v[4*g+0] = -1e30f; v[4*g+1] = -1e30f;
            v[4*g+2] = -1e30f; v[4*g+3] = -1e30f;
        }
    }

#pragma unroll
    for (int j = 0; j < 4; ++j) redm[(j * 8 + widq) * 32 + n] = pmax[j];
    __syncthreads();
    float m[4];
#pragma unroll
    for (int j = 0; j < 4; ++j) {
        float mm = redm[(j * 8 + 0) * 32 + n];
#pragma unroll
        for (int i = 1; i < 8; ++i) mm = fmaxf(mm, redm[(j * 8 + i) * 32 + n]);
        m[j] = mm;
    }

    float psum[4] = {0.f, 0.f, 0.f, 0.f};
#pragma unroll
    for (int g = 0; g < 4; ++g) {
#pragma unroll
        for (int j = 0; j < 4; ++j) {
            float e = expf(v[4*g+j] - m[j]);   // padded rows: exp(-huge) -> 0
            v[4*g+j] = e;
            psum[j] += e;
        }
    }
#pragma unroll
    for (int j = 0; j < 4; ++j) reds[(j * 8 + widq) * 32 + n] = psum[j];
    __syncthreads();
    float inv[4];
#pragma unroll
    for (int j = 0; j < 4; ++j) {
        float ss = reds[(j * 8 + 0) * 32 + n];
#pragma unroll
        for (int i = 1; i < 8; ++i) ss += reds[(j * 8 + i) * 32 + n];
        inv[j] = 1.f / ss;
    }
    __syncthreads();     // all reds/redm reads done before wsL overwrites arena

    // ---- phase 3a: redistribute weights: lane n holds pixel n's rows ----
#pragma unroll
    for (int reg = 0; reg < 16; ++reg) {
        int row = (reg & 3) + 8 * (reg >> 2) + 4 * q;
        int ko  = wid * 32 + row;
        if (ko < KOC) wsL[ko * 32 + n] = v[reg] * inv[reg & 3];
    }
    __syncthreads();

    // ---- phase 3b: CARAFE sweep over this block's 32 channels (4 stages) ----
    int p = tid & 31;                    // pixel within tile
    int s = tid >> 5;                    // 0..7 channel slot
    int w = w0 + p;

    float wt[100];
#pragma unroll
    for (int k = 0; k < 25; ++k) {
#pragma unroll
        for (int j = 0; j < 4; ++j)
            wt[j * 25 + k] = wsL[(4 * k + j) * 32 + p];
    }
    // zero weights of out-of-bounds taps (xs holds clamped values)
#pragma unroll
    for (int ki = 0; ki < 5; ++ki) {
#pragma unroll
        for (int kj = 0; kj < 5; ++kj) {
            int k = ki * 5 + kj;
            int r = h + ki - 2, cc = w + kj - 2;
            bool valid = ((unsigned)r < 64u) && ((unsigned)cc < 64u);
            if (!valid) { wt[k] = 0.f; wt[25+k] = 0.f; wt[50+k] = 0.f; wt[75+k] = 0.f; }
        }
    }

    const int sbase = s * 180;           // xs[s][ki][col], ki stride 36
    const int cbase = cg4 * 32;          // this block's channel range
    for (int g = 0; g < 4; ++g) {
        __syncthreads();                 // previous iteration's xs reads done
        // stage X halo: 8 ch x 5 rows x 36 cols (rows/cols clamped)
        for (int i = tid; i < 8 * 5 * 36; i += 256) {
            int cs  = i / 180;
            int rem = i - cs * 180;
            int r   = rem / 36;
            int col = rem - r * 36;
            int gr  = h - 2 + r;
            int rc  = gr < 0 ? 0 : (gr > 63 ? 63 : gr);
            int gcol = w0 - 2 + col;
            int gcc  = gcol < 0 ? 0 : (gcol > 63 ? 63 : gcol);
            xs[i] = X[((size_t)b * CIN + (cbase + g * 8 + cs)) * HW + rc * 64 + gcc];
        }
        __syncthreads();

        int c = cbase + g * 8 + s;
        float a0 = 0.f, a1 = 0.f, a2 = 0.f, a3 = 0.f;
#pragma unroll
        for (int ki = 0; ki < 5; ++ki) {
#pragma unroll
            for (int kj = 0; kj < 5; ++kj) {
                int k = ki * 5 + kj;
                float xv = xs[sbase + ki * 36 + p + kj];
                a0 += wt[k]      * xv;
                a1 += wt[25 + k] * xv;
                a2 += wt[50 + k] * xv;
                a3 += wt[75 + k] * xv;
            }
        }
        float* o = out + ((size_t)b * CIN + c) * HW2 + (size_t)(2 * h) * W2d + 2 * w;
        *(float2*)o         = make_float2(a0, a1);
        *(float2*)(o + W2d) = make_float2(a2, a3);
    }
}

extern "C" void kernel_launch(void* const* d_in, const int* in_sizes, int n_in,
                              void* d_out, int out_size, void* d_ws, size_t ws_size,
                              hipStream_t stream)
{
    const float* X  = (const float*)d_in[0];
    const float* cw = (const float*)d_in[1];
    const float* cg = (const float*)d_in[2];
    const float* cb = (const float*)d_in[3];
    const float* ew = (const float*)d_in[4];
    const float* eg = (const float*)d_in[5];
    const float* eb = (const float*)d_in[6];
    float* out = (float*)d_out;

    char* ws = (char*)d_ws;
    ushort* W1b = (ushort*)ws;                            // 4*4096*64 bf16 = 2 MB
    ushort* Abf = (ushort*)(ws + 2097152);                // 9*128*64 = 147456 B

    comp_kernel      <<<1024, 256, 0, stream>>>(X, cw, cg, cb, ew, W1b, Abf);
    enc_carafe_kernel<<<2048, 256, 0, stream>>>(W1b, Abf, eg, eb, X, out);
}

// Round 6
// 117.740 us; speedup vs baseline: 1.4375x; 1.4375x over previous
//
#include <hip/hip_runtime.h>
#include <hip/hip_bf16.h>
#include <math.h>

#define Bn   4
#define CIN  128
#define Hh   64
#define Ww   64
#define HW   4096
#define CMID 64
#define KOC  100      // (scale*k_up)^2
#define H2   128
#define W2d  128
#define HW2  16384
#define KUP  5
#define BN_EPS 1e-5f
#define CCH  8        // channels per carafe thread (16 chunks of 8)

typedef __attribute__((ext_vector_type(4)))  short  short4v;
typedef __attribute__((ext_vector_type(8)))  short  short8v;
typedef __attribute__((ext_vector_type(16))) float  float16v;

__device__ __forceinline__ ushort f2bf(float v) {
    __hip_bfloat16 h = __float2bfloat16(v);
    return *(ushort*)&h;
}

// ---------------- Kernel A (v3): 1x1 conv + BN + SiLU -> W1b NHWC bf16
// LDS-tiled GEMM: block = 32 pixels x 64 co, 512 blocks.
// X tile [128 ci][32 pix] + transposed weights cwT[128 ci][66 pad] in LDS;
// all global loads coalesced & per-lane distinct (VMEM instrs 160 -> ~15/thr).
// Thread tile: 4 pix x 2 co; per ci: 1 ds_read_b128 (x) + 1 ds_read_b64 (w).
// Numerics identical to round-2 comp (fp32 FMA, sequential ci order).
// Piggyback A-prep: 144 elems per block (512*144 = 73728 = 9*128*64).
__global__ __launch_bounds__(256) void comp_kernel(
    const float* __restrict__ X,
    const float* __restrict__ cw,
    const float* __restrict__ cg,
    const float* __restrict__ cb,
    const float* __restrict__ ew,
    ushort* __restrict__ W1b,       // [b][pix][64] bf16
    ushort* __restrict__ Abf)       // [9][128][64]
{
    __shared__ float xsS[128 * 32];      // [ci][pix] 16 KB
    __shared__ float cwT[128 * 66];      // [ci][co pad 66] 33.8 KB

    int tid  = threadIdx.x;
    int blk  = blockIdx.x;               // 512: b = blk>>7, tile = blk&127
    int b    = blk >> 7;
    int pix0 = (blk & 127) * 32;

    const float* xb = X + (size_t)b * CIN * HW + pix0;

    // stage X tile: 128 ci x 32 pix (float4 slots, coalesced)
    for (int s = tid; s < 1024; s += 256) {
        int ci = s >> 3, seg = s & 7;
        *(float4*)&xsS[ci * 32 + seg * 4] =
            *(const float4*)(xb + (size_t)ci * HW + seg * 4);
    }
    // stage cw transposed: [ci][co] (coalesced read, scattered LDS write)
    for (int i = tid; i < 8192; i += 256) {
        int co = i >> 7, ci = i & 127;
        cwT[ci * 66 + co] = cw[i];
    }
    // A-prep: elems [blk*144, blk*144+144)
    for (int t = tid; t < 144; t += 256) {
        int i   = blk * 144 + t;
        int cm  = i & 63;
        int kop = (i >> 6) & 127;
        int tap = i >> 13;
        float v = (kop < KOC) ? ew[((size_t)(kop * CMID + cm)) * 9 + tap] : 0.f;
        Abf[i] = f2bf(v);
    }
    __syncthreads();

    int px4 = (tid & 7) * 4;             // 8 pixel-groups of 4
    int co2 = (tid >> 3) * 2;            // 32 co-pairs

    float a00 = 0.f, a01 = 0.f, a02 = 0.f, a03 = 0.f;
    float a10 = 0.f, a11 = 0.f, a12 = 0.f, a13 = 0.f;

#pragma unroll 4
    for (int ci = 0; ci < 128; ++ci) {
        float4 xv = *(const float4*)&xsS[ci * 32 + px4];
        float2 wv = *(const float2*)&cwT[ci * 66 + co2];
        a00 += xv.x * wv.x; a01 += xv.y * wv.x;
        a02 += xv.z * wv.x; a03 += xv.w * wv.x;
        a10 += xv.x * wv.y; a11 += xv.y * wv.y;
        a12 += xv.z * wv.y; a13 += xv.w * wv.y;
    }

    float inv_s = rsqrtf(1.0f + BN_EPS);
    float s0 = cg[co2] * inv_s,     bb0 = cb[co2];
    float s1 = cg[co2 + 1] * inv_s, bb1 = cb[co2 + 1];
    float r0[4] = {a00, a01, a02, a03};
    float r1[4] = {a10, a11, a12, a13};
    unsigned* wp = (unsigned*)W1b + ((size_t)b * HW + pix0 + px4) * 32 + (co2 >> 1);
#pragma unroll
    for (int i = 0; i < 4; ++i) {
        float v0 = r0[i] * s0 + bb0; v0 = v0 / (1.f + expf(-v0));
        float v1 = r1[i] * s1 + bb1; v1 = v1 / (1.f + expf(-v1));
        unsigned pk = (unsigned)f2bf(v0) | ((unsigned)f2bf(v1) << 16);
        wp[(size_t)i * 32] = pk;
    }
}

// ---------------- Kernel B: 3x3 conv as implicit GEMM via MFMA bf16
// (verified round-2 version, unchanged)
// FUSED EPILOGUE: BN + 4-way sub-softmax over k (softmax is PER SUBPIXEL:
// ko mod 4 selects the subpixel; each thread's reg j=reg&3 is exactly one sub).
__global__ __launch_bounds__(256) void enc_kernel(
    const ushort* __restrict__ W1b_us,   // [b][pix][64] bf16
    const ushort* __restrict__ Abf,      // [9][128][64] bf16
    const float* __restrict__ eg,
    const float* __restrict__ eb,
    float* __restrict__ Wsm)             // [b][100][4096] fp32 softmax weights
{
    __shared__ ushort Bs[3 * 34 * 72];   // 14688 B
    __shared__ float  redm[4][8][32];    // per-sub cross-wave max
    __shared__ float  reds[4][8][32];    // per-sub cross-wave sum

    int bid   = blockIdx.x;              // b*128 + h*2 + whalf -> 512 blocks
    int whalf = bid & 1;
    int h     = (bid >> 1) & 63;
    int b     = bid >> 7;
    int w0    = whalf * 32;
    int tid   = threadIdx.x;

    // stage B tile (bf16-pair granularity, coalesced in cm)
    const unsigned* src  = (const unsigned*)W1b_us;  // [b][pix][32] u32 pairs
    unsigned*       dstu = (unsigned*)Bs;            // w-slot stride 36 uints
    for (int i = tid; i < 3 * 34 * 32; i += 256) {
        int cp = i & 31;
        int t  = i >> 5;
        int wl = t % 34;
        int r  = t / 34;
        int gr = h - 1 + r, gw = w0 - 1 + wl;
        unsigned val = 0u;
        if ((unsigned)gr < 64u && (unsigned)gw < 64u)
            val = src[((size_t)b * HW + gr * 64 + gw) * 32 + cp];
        dstu[(r * 34 + wl) * 36 + cp] = val;
    }
    __syncthreads();

    int lane = tid & 63;
    int wid  = tid >> 6;                 // M-tile: ko base = wid*32
    int n    = lane & 31;
    int q    = lane >> 5;                // 0/1 -> k half

    float16v acc;
#pragma unroll
    for (int i = 0; i < 16; ++i) acc[i] = 0.f;

    const ushort* Arow = Abf + ((size_t)(wid * 32 + n)) * 64 + q * 8;

#pragma unroll
    for (int tap = 0; tap < 9; ++tap) {
        int dy = tap / 3, dx = tap % 3;
        int bbase = ((dy * 34) + n + dx) * 72 + q * 8;     // ushort idx, 16B aligned
        const ushort* Atap = Arow + (size_t)tap * 128 * 64;
#pragma unroll
        for (int c = 0; c < 4; ++c) {
            short8v a = *(const short8v*)(Atap + c * 16);
            short8v bf = *(const short8v*)(Bs + bbase + c * 16);
            acc = __builtin_amdgcn_mfma_f32_32x32x16_bf16(a, bf, acc, 0, 0, 0);
        }
    }

    // ---- fused BN + per-subpixel softmax ----
    // reg = 4g+j -> row = j + 8g + 4q -> ko = wid*32 + 8g + 4q + j; ko mod 4 = j.
    float inv_s = rsqrtf(1.0f + BN_EPS);
    int   widq  = wid * 2 + q;

    float v[16];
    float pmax[4] = {-1e30f, -1e30f, -1e30f, -1e30f};
#pragma unroll
    for (int g = 0; g < 4; ++g) {
        int base = wid * 32 + 8 * g + 4 * q;
        if (base < KOC) {
            float4 gg = *(const float4*)(eg + base);
            float4 bb = *(const float4*)(eb + base);
            float v0 = acc[4*g+0] * (gg.x * inv_s) + bb.x;
            float v1 = acc[4*g+1] * (gg.y * inv_s) + bb.y;
            float v2 = acc[4*g+2] * (gg.z * inv_s) + bb.z;
            float v3 = acc[4*g+3] * (gg.w * inv_s) + bb.w;
            v[4*g+0] = v0; v[4*g+1] = v1; v[4*g+2] = v2; v[4*g+3] = v3;
            pmax[0] = fmaxf(pmax[0], v0);
            pmax[1] = fmaxf(pmax[1], v1);
            pmax[2] = fmaxf(pmax[2], v2);
            pmax[3] = fmaxf(pmax[3], v3);
        } else {
            v[4*g+0] = -1e30f; v[4*g+1] = -1e30f;
            v[4*g+2] = -1e30f; v[4*g+3] = -1e30f;
        }
    }

#pragma unroll
    for (int j = 0; j < 4; ++j) redm[j][widq][n] = pmax[j];
    __syncthreads();
    float m[4];
#pragma unroll
    for (int j = 0; j < 4; ++j) {
        float mm = redm[j][0][n];
#pragma unroll
        for (int i = 1; i < 8; ++i) mm = fmaxf(mm, redm[j][i][n]);
        m[j] = mm;
    }

    float psum[4] = {0.f, 0.f, 0.f, 0.f};
#pragma unroll
    for (int g = 0; g < 4; ++g) {
#pragma unroll
        for (int j = 0; j < 4; ++j) {
            float e = expf(v[4*g+j] - m[j]);   // padded rows: exp(-huge) -> 0
            v[4*g+j] = e;
            psum[j] += e;
        }
    }
#pragma unroll
    for (int j = 0; j < 4; ++j) reds[j][widq][n] = psum[j];
    __syncthreads();
    float inv[4];
#pragma unroll
    for (int j = 0; j < 4; ++j) {
        float ss = reds[j][0][n];
#pragma unroll
        for (int i = 1; i < 8; ++i) ss += reds[j][i][n];
        inv[j] = 1.f / ss;
    }

    int pixn = h * 64 + w0 + n;
    float* Wp = Wsm + (size_t)b * KOC * HW + pixn;
#pragma unroll
    for (int reg = 0; reg < 16; ++reg) {
        int row = (reg & 3) + 8 * (reg >> 2) + 4 * q;
        int ko  = wid * 32 + row;
        if (ko < KOC) Wp[(size_t)ko * HW] = v[reg] * inv[reg & 3];
    }
}

// ---------------- Kernel D: CARAFE reassembly (verified round-0 version)
// (parity fold: floor((h2-4+2*ki)/2) = h + ki - 2 for both parities of h2)
__global__ __launch_bounds__(256) void carafe_kernel(
    const float* __restrict__ X,
    const float* __restrict__ Wsm,
    float* __restrict__ out)
{
    int gt = blockIdx.x * blockDim.x + threadIdx.x;    // (chunk*Bn + b)*HW + h*64 + w
    int w  = gt & 63;
    int h  = (gt >> 6) & 63;
    int b  = (gt >> 12) & 3;
    int chunk = gt >> 14;                              // 0..15
    int c0 = chunk * CCH;
    int pix = h * Ww + w;

    float wt[100];
    const float* wpb = Wsm + (size_t)b * KOC * HW + pix;
#pragma unroll
    for (int k = 0; k < 25; ++k) {
        wt[k]      = wpb[(size_t)(4 * k + 0) * HW];
        wt[25 + k] = wpb[(size_t)(4 * k + 1) * HW];
        wt[50 + k] = wpb[(size_t)(4 * k + 2) * HW];
        wt[75 + k] = wpb[(size_t)(4 * k + 3) * HW];
    }

    int off[25];
#pragma unroll
    for (int ki = 0; ki < 5; ++ki) {
#pragma unroll
        for (int kj = 0; kj < 5; ++kj) {
            int k = ki * 5 + kj;
            int r = h + ki - 2, cc = w + kj - 2;
            bool valid = ((unsigned)r < 64u) && ((unsigned)cc < 64u);
            int rc = r < 0 ? 0 : (r > 63 ? 63 : r);
            int cx = cc < 0 ? 0 : (cc > 63 ? 63 : cc);
            off[k] = rc * Ww + cx;
            if (!valid) { wt[k] = 0.f; wt[25+k] = 0.f; wt[50+k] = 0.f; wt[75+k] = 0.f; }
        }
    }

    const float* xp = X + ((size_t)b * CIN + c0) * HW;
    float* o0 = out + ((size_t)b * CIN + c0) * HW2 + (2 * h) * W2d + 2 * w;

    for (int c = 0; c < CCH; ++c) {
        float x[25];
#pragma unroll
        for (int k = 0; k < 25; ++k) x[k] = xp[off[k]];
        float a0 = 0.f, a1 = 0.f, a2 = 0.f, a3 = 0.f;
#pragma unroll
        for (int k = 0; k < 25; ++k) {
            float xv = x[k];
            a0 += wt[k]      * xv;
            a1 += wt[25 + k] * xv;
            a2 += wt[50 + k] * xv;
            a3 += wt[75 + k] * xv;
        }
        *(float2*)o0          = make_float2(a0, a1);
        *(float2*)(o0 + W2d)  = make_float2(a2, a3);
        xp += HW;
        o0 += HW2;
    }
}

extern "C" void kernel_launch(void* const* d_in, const int* in_sizes, int n_in,
                              void* d_out, int out_size, void* d_ws, size_t ws_size,
                              hipStream_t stream)
{
    const float* X  = (const float*)d_in[0];
    const float* cw = (const float*)d_in[1];
    const float* cg = (const float*)d_in[2];
    const float* cb = (const float*)d_in[3];
    const float* ew = (const float*)d_in[4];
    const float* eg = (const float*)d_in[5];
    const float* eb = (const float*)d_in[6];
    float* out = (float*)d_out;

    char* ws = (char*)d_ws;
    ushort* W1b = (ushort*)ws;                            // 4*4096*64 bf16 = 2 MB
    ushort* Abf = (ushort*)(ws + 2097152);                // 9*128*64 = 147456 B
    float*  Wsm = (float*)(ws + 2097152 + 147456);        // 6.55 MB

    comp_kernel  <<<512, 256, 0, stream>>>(X, cw, cg, cb, ew, W1b, Abf);
    enc_kernel   <<<512, 256, 0, stream>>>(W1b, Abf, eg, eb, Wsm);
    carafe_kernel<<<16 * Bn * HW / 256, 256, 0, stream>>>(X, Wsm, out);
}